// Round 4
// baseline (382.758 us; speedup 1.0000x reference)
//
#include <hip/hip_runtime.h>

#define N_NODES 50000
#define N_EDGES 800000
#define IN_F    128
#define HEADS   8
#define OUT_F   16

typedef unsigned short u16;
typedef __attribute__((ext_vector_type(8))) short bf16x8;   // 4 VGPRs
typedef __attribute__((ext_vector_type(4))) float f32x4;

__device__ __forceinline__ float bf2f(u16 u) {
    return __uint_as_float(((unsigned)u) << 16);
}
__device__ __forceinline__ u16 f2bf(float f) {
    unsigned u = __float_as_uint(f);
    unsigned r = 0x7fffu + ((u >> 16) & 1u);
    return (u16)((u + r) >> 16);
}
// dtype-adaptive float load: bf=true -> buffer is bf16, else fp32
__device__ __forceinline__ float ldf(const void* p, int i, bool bf) {
    return bf ? bf2f(((const u16*)p)[i]) : ((const float*)p)[i];
}

// ------------------------------------------------------------- dtype probe
__global__ void probe_dtype(const void* __restrict__ h, int* __restrict__ flag) {
    if (threadIdx.x == 0 && blockIdx.x == 0) {
        const u16* u = (const u16*)h;
        int cnt = 0;
        for (int i = 0; i < 128; ++i) {
            int e = (u[i] >> 7) & 0xFF;
            if (e >= 90 && e <= 141) cnt++;
        }
        *flag = (cnt >= 110) ? 1 : 0;
    }
}

// ---------------------------------------------------------------- init
__global__ __launch_bounds__(256) void zero_counts(int* __restrict__ counts) {
    int i = blockIdx.x * 256 + threadIdx.x;
    if (i < N_NODES) counts[i] = 0;
}

// ------------------------------------------------- node projection (MFMA)
// (unchanged from R3 — verified correct)
#define WT_STRIDE 136
__global__ __launch_bounds__(256) void node_proj_mfma(
    const void* __restrict__ h, const void* __restrict__ Wn,
    const void* __restrict__ a_srcp, const void* __restrict__ a_dstp,
    const int* __restrict__ flag,
    u16* __restrict__ ht, float* __restrict__ s_src, float* __restrict__ s_dst)
{
    const bool bf = (*flag) != 0;
    __shared__ u16 Wsh[IN_F * WT_STRIDE];   // 34.8 KB, Wt[c][k]
    const int tid = threadIdx.x;

    for (int i = tid; i < IN_F * IN_F; i += 256) {
        int k = i >> 7, c = i & 127;
        u16 v = bf ? ((const u16*)Wn)[i] : f2bf(((const float*)Wn)[i]);
        Wsh[c * WT_STRIDE + k] = v;
    }
    __syncthreads();

    const int wave = tid >> 6, lane = tid & 63;
    const int m = lane & 15, q = lane >> 4;
    const int row_t = blockIdx.x * 64 + wave * 16;

    bf16x8 afr[4];
    int arow = row_t + m;
    if (arow >= N_NODES) arow = N_NODES - 1;
    if (bf) {
        const u16* hp = (const u16*)h + (size_t)arow * IN_F;
        #pragma unroll
        for (int kt = 0; kt < 4; ++kt)
            afr[kt] = *(const bf16x8*)(hp + kt * 32 + q * 8);
    } else {
        const float* hp = (const float*)h + (size_t)arow * IN_F;
        #pragma unroll
        for (int kt = 0; kt < 4; ++kt) {
            bf16x8 t;
            #pragma unroll
            for (int j = 0; j < 8; ++j) t[j] = (short)f2bf(hp[kt * 32 + q * 8 + j]);
            afr[kt] = t;
        }
    }

    for (int ct = 0; ct < 8; ++ct) {
        f32x4 acc = {0.f, 0.f, 0.f, 0.f};
        #pragma unroll
        for (int kt = 0; kt < 4; ++kt) {
            bf16x8 bfr = *(const bf16x8*)(Wsh + (ct * 16 + m) * WT_STRIDE + kt * 32 + q * 8);
            acc = __builtin_amdgcn_mfma_f32_16x16x32_bf16(afr[kt], bfr, acc, 0, 0, 0);
        }
        const float asv = ldf(a_srcp, ct * 16 + m, bf);
        const float adv = ldf(a_dstp, ct * 16 + m, bf);
        float v1[4], v2[4];
        #pragma unroll
        for (int r = 0; r < 4; ++r) {
            int grow = row_t + q * 4 + r;
            if (grow < N_NODES)
                ht[(size_t)grow * IN_F + ct * 16 + m] = f2bf(acc[r]);
            v1[r] = acc[r] * asv;
            v2[r] = acc[r] * adv;
        }
        #pragma unroll
        for (int o = 1; o < 16; o <<= 1) {
            #pragma unroll
            for (int r = 0; r < 4; ++r) {
                v1[r] += __shfl_xor(v1[r], o, 16);
                v2[r] += __shfl_xor(v2[r], o, 16);
            }
        }
        if (m == 0) {
            #pragma unroll
            for (int r = 0; r < 4; ++r) {
                int grow = row_t + q * 4 + r;
                if (grow < N_NODES) {
                    s_src[grow * HEADS + ct] = v1[r];
                    s_dst[grow * HEADS + ct] = v2[r];
                }
            }
        }
    }
}

// -------------------------------------------------------- sort-by-dst: hist
__global__ __launch_bounds__(256) void hist_dst(const int* __restrict__ ei,
                                                int* __restrict__ counts) {
    int t = blockIdx.x * 256 + threadIdx.x;
    if (t < N_EDGES) atomicAdd(&counts[ei[N_EDGES + t]], 1);
}

// -------------------------------------------------------- sort: scan (1 blk)
#define SCAN_T 1024
#define SCAN_C 49   // ceil(50000/1024)
__global__ __launch_bounds__(SCAN_T) void scan_offsets(
    const int* __restrict__ counts,
    int* __restrict__ seg_off, int* __restrict__ cursor)
{
    __shared__ int partial[SCAN_T];
    const int t = threadIdx.x;
    const int base = t * SCAN_C;
    int s = 0;
    for (int j = 0; j < SCAN_C; ++j) {
        int i = base + j;
        if (i < N_NODES) s += counts[i];
    }
    partial[t] = s;
    __syncthreads();
    for (int o = 1; o < SCAN_T; o <<= 1) {
        int v = (t >= o) ? partial[t - o] : 0;
        __syncthreads();
        if (t >= o) partial[t] += v;
        __syncthreads();
    }
    int run = (t > 0) ? partial[t - 1] : 0;
    for (int j = 0; j < SCAN_C; ++j) {
        int i = base + j;
        if (i < N_NODES) {
            seg_off[i] = run;
            cursor[i]  = run;
            run += counts[i];
        }
    }
}

// ------------------------------------------------------- sort: scatter edges
__global__ __launch_bounds__(256) void scatter_edges(
    const int* __restrict__ ei, const void* __restrict__ ef,
    const int* __restrict__ flag, int* __restrict__ cursor,
    int* __restrict__ src_s, float* __restrict__ ef_s)
{
    const bool bf = (*flag) != 0;
    int t = blockIdx.x * 256 + threadIdx.x;
    if (t >= N_EDGES) return;
    int s = ei[t], d = ei[N_EDGES + t];
    int pos = atomicAdd(&cursor[d], 1);
    src_s[pos] = s;
    ef_s[pos]  = ldf(ef, t, bf);
}

// ------------------------------------------------- aggregation (dst-grouped)
// 16-lane group per dst node. Lane L reads ht[src, L*8 .. L*8+8) (16 B) ->
// head h = L>>1, feats (L&1)*8+j. Lanes 0..7 compute w for heads 0..7;
// lane L needs head L>>1 via one shfl. Unnormalized per-head accumulate +
// sum-w; normalize + fold head-mean (xor-shuffle over 2,4,8) at the end.
__global__ __launch_bounds__(256) void aggregate(
    const int* __restrict__ seg_off, const int* __restrict__ counts,
    const int* __restrict__ src_s, const float* __restrict__ ef_s,
    const void* __restrict__ We, const int* __restrict__ flag,
    const float* __restrict__ s_src, const float* __restrict__ s_dst,
    const u16* __restrict__ ht, void* __restrict__ out)
{
    const bool bf = (*flag) != 0;
    int g = (blockIdx.x * 256 + threadIdx.x) >> 4;
    if (g >= N_NODES) return;
    const int lane = threadIdx.x & 15;
    const int myh  = lane >> 1;

    const int off = seg_off[g];
    const int deg = counts[g];

    float sdv = 0.0f, wev = 0.0f;
    if (lane < 8) {
        sdv = s_dst[g * HEADS + lane];
        wev = ldf(We, lane, bf);
    }

    float acc[8];
    #pragma unroll
    for (int j = 0; j < 8; ++j) acc[j] = 0.0f;
    float sw = 0.0f;   // sum of w for head myh (identical in lane pairs)

    for (int i = 0; i < deg; ++i) {
        int src = src_s[off + i];
        float w = 0.0f;
        if (lane < 8) {
            float a = s_src[src * HEADS + lane] + sdv + ef_s[off + i] * wev;
            a = (a > 0.0f) ? a : 0.2f * a;
            w = __expf(a);
        }
        float wv = __shfl(w, myh, 16);
        bf16x8 v8 = *(const bf16x8*)(ht + (size_t)src * IN_F + lane * 8);
        #pragma unroll
        for (int j = 0; j < 8; ++j)
            acc[j] = fmaf(wv, bf2f((u16)v8[j]), acc[j]);
        sw += wv;
    }

    const float inv = 1.0f / fmaxf(sw, 1e-12f);
    #pragma unroll
    for (int j = 0; j < 8; ++j) acc[j] *= inv;

    // fold head-mean: sum over the 8 lanes of same parity (strides 2,4,8)
    #pragma unroll
    for (int o = 2; o < 16; o <<= 1) {
        #pragma unroll
        for (int j = 0; j < 8; ++j)
            acc[j] += __shfl_xor(acc[j], o, 16);
    }

    if (lane < 2) {   // lane 0: feats 0..7, lane 1: feats 8..15
        if (bf) {
            u16* op = (u16*)out + g * OUT_F + lane * 8;
            bf16x8 o8;
            #pragma unroll
            for (int j = 0; j < 8; ++j) o8[j] = (short)f2bf(acc[j] * 0.125f);
            *(bf16x8*)op = o8;
        } else {
            float* op = (float*)out + g * OUT_F + lane * 8;
            #pragma unroll
            for (int j = 0; j < 8; ++j) op[j] = acc[j] * 0.125f;
        }
    }
}

// ---------------------------------------------------------------- launch
extern "C" void kernel_launch(void* const* d_in, const int* in_sizes, int n_in,
                              void* d_out, int out_size, void* d_ws, size_t ws_size,
                              hipStream_t stream) {
    const void* h     = d_in[0];
    const int*  ei    = (const int*)d_in[1];
    const void* efeat = d_in[2];
    const void* Wn    = d_in[3];
    const void* We    = d_in[4];
    const void* a_src = d_in[5];
    const void* a_dst = d_in[6];

    char* ws = (char*)d_ws;
    int*   flag    = (int*)ws;   ws += 256;
    u16*   ht      = (u16*)ws;   ws += (size_t)N_NODES * IN_F * 2;    // 12.8 MB
    float* s_src   = (float*)ws; ws += (size_t)N_NODES * HEADS * 4;   // 1.6 MB
    float* s_dst   = (float*)ws; ws += (size_t)N_NODES * HEADS * 4;   // 1.6 MB
    int*   counts  = (int*)ws;   ws += (size_t)N_NODES * 4;
    int*   seg_off = (int*)ws;   ws += (size_t)N_NODES * 4;
    int*   cursor  = (int*)ws;   ws += (size_t)N_NODES * 4;
    int*   src_s   = (int*)ws;   ws += (size_t)N_EDGES * 4;           // 3.2 MB
    float* ef_s    = (float*)ws; ws += (size_t)N_EDGES * 4;           // 3.2 MB

    hipLaunchKernelGGL(probe_dtype, dim3(1), dim3(64), 0, stream, h, flag);
    hipLaunchKernelGGL(zero_counts, dim3((N_NODES + 255) / 256), dim3(256),
                       0, stream, counts);
    hipLaunchKernelGGL(node_proj_mfma, dim3((N_NODES + 63) / 64), dim3(256),
                       0, stream, h, Wn, a_src, a_dst, flag, ht, s_src, s_dst);
    hipLaunchKernelGGL(hist_dst, dim3((N_EDGES + 255) / 256), dim3(256),
                       0, stream, ei, counts);
    hipLaunchKernelGGL(scan_offsets, dim3(1), dim3(SCAN_T), 0, stream,
                       counts, seg_off, cursor);
    hipLaunchKernelGGL(scatter_edges, dim3((N_EDGES + 255) / 256), dim3(256),
                       0, stream, ei, efeat, flag, cursor, src_s, ef_s);
    hipLaunchKernelGGL(aggregate, dim3((N_NODES * 16 + 255) / 256), dim3(256),
                       0, stream, seg_off, counts, src_s, ef_s, We, flag,
                       s_src, s_dst, ht, d_out);
}

// Round 5
// 264.493 us; speedup vs baseline: 1.4471x; 1.4471x over previous
//
#include <hip/hip_runtime.h>

#define N_NODES 50000
#define N_EDGES 800000
#define IN_F    128
#define HEADS   8
#define OUT_F   16

typedef unsigned short u16;
typedef __attribute__((ext_vector_type(8))) short bf16x8;   // 4 VGPRs
typedef __attribute__((ext_vector_type(4))) float f32x4;

__device__ __forceinline__ float bf2f(u16 u) {
    return __uint_as_float(((unsigned)u) << 16);
}
__device__ __forceinline__ u16 f2bf(float f) {
    unsigned u = __float_as_uint(f);
    unsigned r = 0x7fffu + ((u >> 16) & 1u);
    return (u16)((u + r) >> 16);
}
// dtype-adaptive float load: bf=true -> buffer is bf16, else fp32
__device__ __forceinline__ float ldf(const void* p, int i, bool bf) {
    return bf ? bf2f(((const u16*)p)[i]) : ((const float*)p)[i];
}

// ------------------------------------------------------------- dtype probe
__global__ void probe_dtype(const void* __restrict__ h, int* __restrict__ flag) {
    const u16* u = (const u16*)h;
    int t = threadIdx.x;           // 64 threads
    int good = 0;
    #pragma unroll
    for (int j = 0; j < 2; ++j) {
        int e = (u[t * 2 + j] >> 7) & 0xFF;
        good += (e >= 90 && e <= 141) ? 1 : 0;
    }
    #pragma unroll
    for (int o = 32; o; o >>= 1) good += __shfl_down(good, o, 64);
    if (t == 0) *flag = (good >= 110) ? 1 : 0;
}

// ---------------------------------------------------------------- init
__global__ __launch_bounds__(256) void zero_counts(int* __restrict__ counts,
                                                   int* __restrict__ total) {
    int i = blockIdx.x * 256 + threadIdx.x;
    if (i < N_NODES) counts[i] = 0;
    if (i == 0) *total = 0;
}

// ------------------------------------------------- node projection (MFMA)
#define WT_STRIDE 136
__global__ __launch_bounds__(256) void node_proj_mfma(
    const void* __restrict__ h, const void* __restrict__ Wn,
    const void* __restrict__ a_srcp, const void* __restrict__ a_dstp,
    const int* __restrict__ flag,
    u16* __restrict__ ht, float* __restrict__ s_src, float* __restrict__ s_dst)
{
    const bool bf = (*flag) != 0;
    __shared__ u16 Wsh[IN_F * WT_STRIDE];   // 34.8 KB, Wt[c][k]
    const int tid = threadIdx.x;

    for (int i = tid; i < IN_F * IN_F; i += 256) {
        int k = i >> 7, c = i & 127;
        u16 v = bf ? ((const u16*)Wn)[i] : f2bf(((const float*)Wn)[i]);
        Wsh[c * WT_STRIDE + k] = v;
    }
    __syncthreads();

    const int wave = tid >> 6, lane = tid & 63;
    const int m = lane & 15, q = lane >> 4;
    const int row_t = blockIdx.x * 64 + wave * 16;

    bf16x8 afr[4];
    int arow = row_t + m;
    if (arow >= N_NODES) arow = N_NODES - 1;
    if (bf) {
        const u16* hp = (const u16*)h + (size_t)arow * IN_F;
        #pragma unroll
        for (int kt = 0; kt < 4; ++kt)
            afr[kt] = *(const bf16x8*)(hp + kt * 32 + q * 8);
    } else {
        const float* hp = (const float*)h + (size_t)arow * IN_F;
        #pragma unroll
        for (int kt = 0; kt < 4; ++kt) {
            bf16x8 t;
            #pragma unroll
            for (int j = 0; j < 8; ++j) t[j] = (short)f2bf(hp[kt * 32 + q * 8 + j]);
            afr[kt] = t;
        }
    }

    for (int ct = 0; ct < 8; ++ct) {
        f32x4 acc = {0.f, 0.f, 0.f, 0.f};
        #pragma unroll
        for (int kt = 0; kt < 4; ++kt) {
            bf16x8 bfr = *(const bf16x8*)(Wsh + (ct * 16 + m) * WT_STRIDE + kt * 32 + q * 8);
            acc = __builtin_amdgcn_mfma_f32_16x16x32_bf16(afr[kt], bfr, acc, 0, 0, 0);
        }
        const float asv = ldf(a_srcp, ct * 16 + m, bf);
        const float adv = ldf(a_dstp, ct * 16 + m, bf);
        float v1[4], v2[4];
        #pragma unroll
        for (int r = 0; r < 4; ++r) {
            int grow = row_t + q * 4 + r;
            if (grow < N_NODES)
                ht[(size_t)grow * IN_F + ct * 16 + m] = f2bf(acc[r]);
            v1[r] = acc[r] * asv;
            v2[r] = acc[r] * adv;
        }
        #pragma unroll
        for (int o = 1; o < 16; o <<= 1) {
            #pragma unroll
            for (int r = 0; r < 4; ++r) {
                v1[r] += __shfl_xor(v1[r], o, 16);
                v2[r] += __shfl_xor(v2[r], o, 16);
            }
        }
        if (m == 0) {
            #pragma unroll
            for (int r = 0; r < 4; ++r) {
                int grow = row_t + q * 4 + r;
                if (grow < N_NODES) {
                    s_src[grow * HEADS + ct] = v1[r];
                    s_dst[grow * HEADS + ct] = v2[r];
                }
            }
        }
    }
}

// -------------------------------------------------------- sort-by-dst: hist
__global__ __launch_bounds__(256) void hist_dst(const int* __restrict__ ei,
                                                int* __restrict__ counts) {
    int t = blockIdx.x * 256 + threadIdx.x;
    if (t < N_EDGES) atomicAdd(&counts[ei[N_EDGES + t]], 1);
}

// ---------------------------------------------- segment alloc (order-free)
// Segment contiguity is all aggregate needs; global order is irrelevant.
// Wave prefix-sum of counts + ONE atomicAdd per wave on a global cursor.
__global__ __launch_bounds__(256) void alloc_offsets(
    const int* __restrict__ counts, int* __restrict__ seg_off,
    int* __restrict__ cursor, int* __restrict__ total)
{
    int i = blockIdx.x * 256 + threadIdx.x;
    int lane = threadIdx.x & 63;
    int c = (i < N_NODES) ? counts[i] : 0;
    int pre = c;   // inclusive prefix within wave
    #pragma unroll
    for (int o = 1; o < 64; o <<= 1) {
        int v = __shfl_up(pre, o, 64);
        if (lane >= o) pre += v;
    }
    int wtot = __shfl(pre, 63, 64);
    int base = 0;
    if (lane == 63) base = atomicAdd(total, wtot);
    base = __shfl(base, 63, 64);
    if (i < N_NODES) {
        int off = base + pre - c;   // exclusive
        seg_off[i] = off;
        cursor[i]  = off;
    }
}

// ------------------------------------------------------- sort: scatter edges
__global__ __launch_bounds__(256) void scatter_edges(
    const int* __restrict__ ei, const void* __restrict__ ef,
    const int* __restrict__ flag, int* __restrict__ cursor,
    int* __restrict__ src_s, float* __restrict__ ef_s)
{
    const bool bf = (*flag) != 0;
    int t = blockIdx.x * 256 + threadIdx.x;
    if (t >= N_EDGES) return;
    int s = ei[t], d = ei[N_EDGES + t];
    int pos = atomicAdd(&cursor[d], 1);
    src_s[pos] = s;
    ef_s[pos]  = ldf(ef, t, bf);
}

// ------------------------------------------------- aggregation (wave/node)
// One wave per dst node. 4 edge-slots x 16 lanes: slot s walks edges
// i = s, s+4, s+8, ... (4 independent gather chains -> 4x MLP).
// Within a slot: lane L reads ht[src, L*8..L*8+8) (16 B); lanes 0..7
// compute w for heads 0..7; lane L gets head L>>1 via width-16 shfl.
// Slot partials folded via xor-shuffle (16,32), then normalize + head-mean.
__global__ __launch_bounds__(256) void aggregate(
    const int* __restrict__ seg_off, const int* __restrict__ counts,
    const int* __restrict__ src_s, const float* __restrict__ ef_s,
    const void* __restrict__ We, const int* __restrict__ flag,
    const float* __restrict__ s_src, const float* __restrict__ s_dst,
    const u16* __restrict__ ht, void* __restrict__ out)
{
    const bool bf = (*flag) != 0;
    int g = (blockIdx.x * 256 + threadIdx.x) >> 6;   // node id (wave)
    if (g >= N_NODES) return;
    const int lane = threadIdx.x & 63;
    const int slot = lane >> 4;     // 0..3
    const int sl   = lane & 15;
    const int myh  = sl >> 1;

    const int off = seg_off[g];
    const int deg = counts[g];

    float sdv = 0.0f, wev = 0.0f;
    if (sl < 8) {
        sdv = s_dst[g * HEADS + sl];
        wev = ldf(We, sl, bf);
    }

    float acc[8];
    #pragma unroll
    for (int j = 0; j < 8; ++j) acc[j] = 0.0f;
    float sw = 0.0f;

    for (int i = slot; i < deg; i += 4) {
        int src = src_s[off + i];
        float w = 0.0f;
        if (sl < 8) {
            float a = s_src[src * HEADS + sl] + sdv + ef_s[off + i] * wev;
            a = (a > 0.0f) ? a : 0.2f * a;
            w = __expf(a);
        }
        float wv = __shfl(w, myh, 16);   // head sl>>1 weight, within slot
        bf16x8 v8 = *(const bf16x8*)(ht + (size_t)src * IN_F + sl * 8);
        #pragma unroll
        for (int j = 0; j < 8; ++j)
            acc[j] = fmaf(wv, bf2f((u16)v8[j]), acc[j]);
        sw += wv;
    }

    // fold the 4 slots (lanes differing in bits 4,5)
    #pragma unroll
    for (int o = 16; o < 64; o <<= 1) {
        sw += __shfl_xor(sw, o, 64);
        #pragma unroll
        for (int j = 0; j < 8; ++j)
            acc[j] += __shfl_xor(acc[j], o, 64);
    }

    const float inv = 1.0f / fmaxf(sw, 1e-12f);
    #pragma unroll
    for (int j = 0; j < 8; ++j) acc[j] *= inv;

    // head-mean: sum the 8 same-parity lanes within the 16-lane segment
    #pragma unroll
    for (int o = 2; o < 16; o <<= 1) {
        #pragma unroll
        for (int j = 0; j < 8; ++j)
            acc[j] += __shfl_xor(acc[j], o, 16);
    }

    if (lane < 2) {   // slot 0: lane 0 feats 0..7, lane 1 feats 8..15
        if (bf) {
            u16* op = (u16*)out + g * OUT_F + lane * 8;
            bf16x8 o8;
            #pragma unroll
            for (int j = 0; j < 8; ++j) o8[j] = (short)f2bf(acc[j] * 0.125f);
            *(bf16x8*)op = o8;
        } else {
            float* op = (float*)out + g * OUT_F + lane * 8;
            #pragma unroll
            for (int j = 0; j < 8; ++j) op[j] = acc[j] * 0.125f;
        }
    }
}

// ---------------------------------------------------------------- launch
extern "C" void kernel_launch(void* const* d_in, const int* in_sizes, int n_in,
                              void* d_out, int out_size, void* d_ws, size_t ws_size,
                              hipStream_t stream) {
    const void* h     = d_in[0];
    const int*  ei    = (const int*)d_in[1];
    const void* efeat = d_in[2];
    const void* Wn    = d_in[3];
    const void* We    = d_in[4];
    const void* a_src = d_in[5];
    const void* a_dst = d_in[6];

    char* ws = (char*)d_ws;
    int*   flag    = (int*)ws;   ws += 128;
    int*   total   = (int*)ws;   ws += 128;
    u16*   ht      = (u16*)ws;   ws += (size_t)N_NODES * IN_F * 2;    // 12.8 MB
    float* s_src   = (float*)ws; ws += (size_t)N_NODES * HEADS * 4;   // 1.6 MB
    float* s_dst   = (float*)ws; ws += (size_t)N_NODES * HEADS * 4;   // 1.6 MB
    int*   counts  = (int*)ws;   ws += (size_t)N_NODES * 4;
    int*   seg_off = (int*)ws;   ws += (size_t)N_NODES * 4;
    int*   cursor  = (int*)ws;   ws += (size_t)N_NODES * 4;
    int*   src_s   = (int*)ws;   ws += (size_t)N_EDGES * 4;           // 3.2 MB
    float* ef_s    = (float*)ws; ws += (size_t)N_EDGES * 4;           // 3.2 MB

    hipLaunchKernelGGL(probe_dtype, dim3(1), dim3(64), 0, stream, h, flag);
    hipLaunchKernelGGL(zero_counts, dim3((N_NODES + 255) / 256), dim3(256),
                       0, stream, counts, total);
    hipLaunchKernelGGL(node_proj_mfma, dim3((N_NODES + 63) / 64), dim3(256),
                       0, stream, h, Wn, a_src, a_dst, flag, ht, s_src, s_dst);
    hipLaunchKernelGGL(hist_dst, dim3((N_EDGES + 255) / 256), dim3(256),
                       0, stream, ei, counts);
    hipLaunchKernelGGL(alloc_offsets, dim3((N_NODES + 255) / 256), dim3(256),
                       0, stream, counts, seg_off, cursor, total);
    hipLaunchKernelGGL(scatter_edges, dim3((N_EDGES + 255) / 256), dim3(256),
                       0, stream, ei, efeat, flag, cursor, src_s, ef_s);
    hipLaunchKernelGGL(aggregate, dim3(((size_t)N_NODES * 64 + 255) / 256), dim3(256),
                       0, stream, seg_off, counts, src_s, ef_s, We, flag,
                       s_src, s_dst, ht, d_out);
}